// Round 1
// baseline (310.845 us; speedup 1.0000x reference)
//
#include <hip/hip_runtime.h>
#include <hip/hip_bf16.h>

typedef __attribute__((ext_vector_type(8))) short short8;
typedef __attribute__((ext_vector_type(4))) float float4v;
typedef __attribute__((ext_vector_type(4))) unsigned int uint4v;

#define SS 8192
#define EE 512
#define HH 64
#define AS 520      // A_lds row stride in shorts (512 + 8 pad -> conflict-free b128)
#define WS 40       // W_lds row stride in shorts (32 + 8 pad)
#define NKB 16      // K steps of 32

__device__ __forceinline__ unsigned int f2bf1(float f) {
    unsigned int u = __builtin_bit_cast(unsigned int, f);
    return (u + 0x7fffu + ((u >> 16) & 1u)) >> 16;   // RNE, inputs are finite
}
__device__ __forceinline__ unsigned int pack2(float lo, float hi) {
    return f2bf1(lo) | (f2bf1(hi) << 16);
}

// One block: batch b, s-chunk sc (64 s rows), n-tile (128 cols).
// Computes Y rows i = h*128 + sc for all 64 heads h, cols [ntile*128, +128).
__global__ __launch_bounds__(256, 2)
void qmha_fused(const float* __restrict__ x, const float* __restrict__ theta,
                const float* __restrict__ W, float* __restrict__ out)
{
    __shared__ __attribute__((aligned(16))) unsigned short A_lds[HH * AS];   // 66560 B
    __shared__ __attribute__((aligned(16))) unsigned short W_lds[128 * WS];  // 10240 B

    const int bx    = blockIdx.x;
    // swizzle: the 4 n-tiles sharing an x-chunk sit 8 apart -> same XCD (n%8 rr)
    const int ntile = (bx >> 3) & 3;
    const int p     = ((bx >> 5) << 3) | (bx & 7);   // 0..1023 = (b, sc)
    const int b     = p >> 7;
    const int sc    = p & 127;

    const int t    = threadIdx.x;
    const int lane = t & 63;
    const int wid  = t >> 6;

    // ---- W prefetch, slice 0 (fp32, convert to bf16 at LDS-commit time) ----
    const int wn = t >> 1;             // 0..127 local n
    const int wk = (t & 1) * 16;       // 0 or 16 within BK=32
    const float* Wbase = W + (size_t)(ntile * 128 + wn) * EE + wk;
    float4v wv0 = *(const float4v*)(Wbase + 0);
    float4v wv1 = *(const float4v*)(Wbase + 4);
    float4v wv2 = *(const float4v*)(Wbase + 8);
    float4v wv3 = *(const float4v*)(Wbase + 12);

    const float th0 = theta[0], th1 = theta[1], th2 = theta[2], th3 = theta[3];
    const float th4 = theta[4], th5 = theta[5], th6 = theta[6], th7 = theta[7];

    // ---- A staging: x[b, sc*64 .. +64, :] coalesced -> cos -> bf16 -> A_lds[h][j]
    // A_lds[h][j] = cos(x[b, sc*64 + (j>>3), 8h + (j&7)] + theta[j&7])
    {
        const float* xb = x + ((size_t)b * SS + (size_t)sc * 64) * EE + lane * 8;
        #pragma unroll
        for (int it = 0; it < 16; ++it) {
            const int s_loc = wid * 16 + it;           // wave w handles 16 s rows
            const float* px = xb + (size_t)s_loc * EE; // wave reads 2KB contiguous
            float4v v0 = *(const float4v*)(px);
            float4v v1 = *(const float4v*)(px + 4);
            float c0 = __cosf(v0.x + th0);
            float c1 = __cosf(v0.y + th1);
            float c2 = __cosf(v0.z + th2);
            float c3 = __cosf(v0.w + th3);
            float c4 = __cosf(v1.x + th4);
            float c5 = __cosf(v1.y + th5);
            float c6 = __cosf(v1.z + th6);
            float c7 = __cosf(v1.w + th7);
            uint4v pk = { pack2(c0,c1), pack2(c2,c3), pack2(c4,c5), pack2(c6,c7) };
            *(uint4v*)&A_lds[lane * AS + s_loc * 8] = pk;   // b128, stride 1040B: conflict-free
        }
    }

    // ---- accumulators: wave tile 32 (m) x 64 (n), 2x4 tiles of 16x16 ----
    float4v acc[2][4];
    #pragma unroll
    for (int i = 0; i < 2; ++i)
        #pragma unroll
        for (int j = 0; j < 4; ++j)
            acc[i][j] = (float4v){0.f, 0.f, 0.f, 0.f};

    const int m0  = (wid >> 1) * 32;   // wave m-offset (heads)
    const int n0l = (wid & 1) * 64;    // wave n-offset within 128-tile
    const int fr  = lane & 15;         // frag row (A) / col (B)
    const int q   = lane >> 4;         // 0..3, k-chunk = q*8

    const unsigned short* Arow0 = &A_lds[(m0 + fr) * AS + q * 8];
    const unsigned short* Arow1 = Arow0 + 16 * AS;
    const unsigned short* Wrow  = &W_lds[(n0l + fr) * WS + q * 8];

    for (int kb = 0; kb < NKB; ++kb) {
        __syncthreads();   // kb=0: A_lds ready; else: all waves done reading W_lds
        // commit prefetched W slice (fp32 regs -> bf16 -> LDS)
        {
            uint4v lo = { pack2(wv0.x, wv0.y), pack2(wv0.z, wv0.w),
                          pack2(wv1.x, wv1.y), pack2(wv1.z, wv1.w) };
            uint4v hi = { pack2(wv2.x, wv2.y), pack2(wv2.z, wv2.w),
                          pack2(wv3.x, wv3.y), pack2(wv3.z, wv3.w) };
            *(uint4v*)&W_lds[wn * WS + wk]     = lo;
            *(uint4v*)&W_lds[wn * WS + wk + 8] = hi;
        }
        if (kb < NKB - 1) {            // async prefetch next slice into regs
            const float* Wn = Wbase + (size_t)(kb + 1) * 32;
            wv0 = *(const float4v*)(Wn + 0);
            wv1 = *(const float4v*)(Wn + 4);
            wv2 = *(const float4v*)(Wn + 8);
            wv3 = *(const float4v*)(Wn + 12);
        }
        __syncthreads();   // W_lds ready

        short8 a0 = *(const short8*)(Arow0 + kb * 32);
        short8 a1 = *(const short8*)(Arow1 + kb * 32);
        short8 b0 = *(const short8*)(Wrow + 0 * 16 * WS);
        short8 b1 = *(const short8*)(Wrow + 1 * 16 * WS);
        short8 b2 = *(const short8*)(Wrow + 2 * 16 * WS);
        short8 b3 = *(const short8*)(Wrow + 3 * 16 * WS);

        acc[0][0] = __builtin_amdgcn_mfma_f32_16x16x32_bf16(a0, b0, acc[0][0], 0, 0, 0);
        acc[0][1] = __builtin_amdgcn_mfma_f32_16x16x32_bf16(a0, b1, acc[0][1], 0, 0, 0);
        acc[0][2] = __builtin_amdgcn_mfma_f32_16x16x32_bf16(a0, b2, acc[0][2], 0, 0, 0);
        acc[0][3] = __builtin_amdgcn_mfma_f32_16x16x32_bf16(a0, b3, acc[0][3], 0, 0, 0);
        acc[1][0] = __builtin_amdgcn_mfma_f32_16x16x32_bf16(a1, b0, acc[1][0], 0, 0, 0);
        acc[1][1] = __builtin_amdgcn_mfma_f32_16x16x32_bf16(a1, b1, acc[1][1], 0, 0, 0);
        acc[1][2] = __builtin_amdgcn_mfma_f32_16x16x32_bf16(a1, b2, acc[1][2], 0, 0, 0);
        acc[1][3] = __builtin_amdgcn_mfma_f32_16x16x32_bf16(a1, b3, acc[1][3], 0, 0, 0);
    }

    // ---- epilogue: C/D layout col=lane&15, row=(lane>>4)*4+reg [m89-verified] ----
    const int colbase = ntile * 128 + n0l + fr;
    #pragma unroll
    for (int mt = 0; mt < 2; ++mt) {
        #pragma unroll
        for (int r = 0; r < 4; ++r) {
            const int hrow = m0 + mt * 16 + q * 4 + r;       // head index = M row
            float* po = out + ((size_t)b * SS + (size_t)hrow * 128 + sc) * EE + colbase;
            po[0 * 16] = acc[mt][0][r];
            po[1 * 16] = acc[mt][1][r];
            po[2 * 16] = acc[mt][2][r];
            po[3 * 16] = acc[mt][3][r];
        }
    }
}

extern "C" void kernel_launch(void* const* d_in, const int* in_sizes, int n_in,
                              void* d_out, int out_size, void* d_ws, size_t ws_size,
                              hipStream_t stream) {
    const float* x     = (const float*)d_in[0];
    const float* theta = (const float*)d_in[1];
    const float* W     = (const float*)d_in[2];
    float* out         = (float*)d_out;

    // grid: 8 batches x 128 s-chunks x 4 n-tiles = 4096 blocks
    qmha_fused<<<dim3(4096), dim3(256), 0, stream>>>(x, theta, W, out);
}

// Round 5
// 282.680 us; speedup vs baseline: 1.0996x; 1.0996x over previous
//
#include <hip/hip_runtime.h>
#include <hip/hip_bf16.h>

typedef __attribute__((ext_vector_type(8))) short short8;
typedef __attribute__((ext_vector_type(4))) float float4v;
typedef __attribute__((ext_vector_type(4))) unsigned int uint4v;
typedef __attribute__((ext_vector_type(2))) unsigned int uint2v;

#define SS 8192
#define EE 512
#define HH 64
#define NKB 16

__device__ __forceinline__ unsigned int f2bf1(float f) {
    unsigned int u = __builtin_bit_cast(unsigned int, f);
    return (u + 0x7fffu + ((u >> 16) & 1u)) >> 16;   // RNE, inputs finite
}
__device__ __forceinline__ unsigned int pack2(float lo, float hi) {
    return f2bf1(lo) | (f2bf1(hi) << 16);
}
__device__ __forceinline__ void gl_lds16(const void* g, void* l) {
    __builtin_amdgcn_global_load_lds(
        (const __attribute__((address_space(1))) void*)g,
        (__attribute__((address_space(3))) void*)l, 16, 0, 0);
}

// ---------- prep: W fp32 [512][512] -> bf16 tiled ws [ntile][kb][n][k32] ----------
__global__ void w_prep(const float* __restrict__ W, unsigned short* __restrict__ Wws) {
    int idx = blockIdx.x * 256 + threadIdx.x;        // 65536 threads x 4 elems
    int r  = idx >> 7;                               // row 0..511 (n-tile major)
    int kg = idx & 127;                              // k-group of 4
    int k  = kg * 4;
    float4v v = *(const float4v*)(W + (size_t)r * EE + k);
    int ntile = r >> 7, n = r & 127, kb = k >> 5, kk = k & 31;
    unsigned short* dst = Wws + (((size_t)(ntile * 16 + kb) * 128 + n) * 32 + kk);
    uint2v pk = { pack2(v.x, v.y), pack2(v.z, v.w) };
    *(uint2v*)dst = pk;
}

// ---------- main: fused cos->bf16 A in LDS, W via async global_load_lds ----------
// A_lds XOR-swizzled: elem [h][j] at shorts h*512 + ((j>>3) ^ (h&7))*8 + (j&7)
__global__ __launch_bounds__(256, 2)
void qmha_fused2(const float* __restrict__ x, const float* __restrict__ theta,
                 const unsigned short* __restrict__ Wws, float* __restrict__ out)
{
    __shared__ __attribute__((aligned(16))) unsigned short A_lds[HH * 512];     // 65536 B
    __shared__ __attribute__((aligned(16))) unsigned short W_lds[2][128 * 32];  // 2 x 8192 B

    const int bx    = blockIdx.x;
    const int ntile = (bx >> 3) & 3;                 // 4 ntiles of same chunk on same XCD
    const int p     = ((bx >> 5) << 3) | (bx & 7);
    const int b     = p >> 7;
    const int sc    = p & 127;

    const int t = threadIdx.x, lane = t & 63, wid = t >> 6;

    const unsigned short* Wtile = Wws + (size_t)ntile * 16 * 4096;  // 16 slices of 4096 shorts

    // DMA W slice 0. One gl_lds16 call = 64 lanes x 16B = 512 shorts (wave-uniform
    // base + lane*16). Wave wid covers shorts [wid*1024, (wid+1)*1024) via 2 calls.
    const int woff = wid * 1024 + lane * 8;          // shorts
    {
        gl_lds16(Wtile + woff,       (unsigned short*)W_lds[0] + woff);
        gl_lds16(Wtile + woff + 512, (unsigned short*)W_lds[0] + woff + 512);
    }

    const float th0 = theta[0], th1 = theta[1], th2 = theta[2], th3 = theta[3];
    const float th4 = theta[4], th5 = theta[5], th6 = theta[6], th7 = theta[7];

    // A staging: x[b, sc*64 .. +64, :] -> cos -> bf16 -> swizzled A_lds
    {
        const float* xb = x + ((size_t)b * SS + (size_t)sc * 64) * EE + lane * 8;
        const int sw = lane & 7;
        #pragma unroll
        for (int it = 0; it < 16; ++it) {
            const int s_loc = wid * 16 + it;
            const float* px = xb + (size_t)s_loc * EE;
            float4v v0 = *(const float4v*)(px);
            float4v v1 = *(const float4v*)(px + 4);
            float c0 = __cosf(v0.x + th0);
            float c1 = __cosf(v0.y + th1);
            float c2 = __cosf(v0.z + th2);
            float c3 = __cosf(v0.w + th3);
            float c4 = __cosf(v1.x + th4);
            float c5 = __cosf(v1.y + th5);
            float c6 = __cosf(v1.z + th6);
            float c7 = __cosf(v1.w + th7);
            uint4v pk = { pack2(c0,c1), pack2(c2,c3), pack2(c4,c5), pack2(c6,c7) };
            *(uint4v*)&A_lds[lane * 512 + ((s_loc ^ sw) * 8)] = pk;
        }
    }

    float4v acc[2][4];
    #pragma unroll
    for (int i = 0; i < 2; ++i)
        #pragma unroll
        for (int j = 0; j < 4; ++j)
            acc[i][j] = (float4v){0.f, 0.f, 0.f, 0.f};

    const int m0  = (wid >> 1) * 32;
    const int n0l = (wid & 1) * 64;
    const int fr  = lane & 15;
    const int q   = lane >> 4;
    const int swA = fr & 7;                          // (m0+fr)&7 == fr&7 since m0%32==0
    const int aBase0 = (m0 + fr) * 512;
    const int aBase1 = aBase0 + 16 * 512;
    const int bOff   = (n0l + fr) * 32 + q * 8;      // unpadded stride-32: conflict-free

    __syncthreads();   // A writes visible + W slice 0 DMA drained (vmcnt(0) @ barrier)

    for (int kb = 0; kb < NKB; ++kb) {
        if (kb < NKB - 1) {                          // async DMA next W slice
            const unsigned short* Ws = Wtile + (size_t)(kb + 1) * 4096;
            unsigned short* Wd = (unsigned short*)W_lds[(kb + 1) & 1];
            gl_lds16(Ws + woff,       Wd + woff);
            gl_lds16(Ws + woff + 512, Wd + woff + 512);
        }
        const unsigned short* Bbuf = (const unsigned short*)W_lds[kb & 1];
        const int g = ((kb * 4 + q) ^ swA) * 8;

        short8 a0 = *(const short8*)&A_lds[aBase0 + g];
        short8 a1 = *(const short8*)&A_lds[aBase1 + g];
        short8 b0 = *(const short8*)&Bbuf[bOff + 0 * 16 * 32];
        short8 b1 = *(const short8*)&Bbuf[bOff + 1 * 16 * 32];
        short8 b2 = *(const short8*)&Bbuf[bOff + 2 * 16 * 32];
        short8 b3 = *(const short8*)&Bbuf[bOff + 3 * 16 * 32];

        acc[0][0] = __builtin_amdgcn_mfma_f32_16x16x32_bf16(a0, b0, acc[0][0], 0, 0, 0);
        acc[0][1] = __builtin_amdgcn_mfma_f32_16x16x32_bf16(a0, b1, acc[0][1], 0, 0, 0);
        acc[0][2] = __builtin_amdgcn_mfma_f32_16x16x32_bf16(a0, b2, acc[0][2], 0, 0, 0);
        acc[0][3] = __builtin_amdgcn_mfma_f32_16x16x32_bf16(a0, b3, acc[0][3], 0, 0, 0);
        acc[1][0] = __builtin_amdgcn_mfma_f32_16x16x32_bf16(a1, b0, acc[1][0], 0, 0, 0);
        acc[1][1] = __builtin_amdgcn_mfma_f32_16x16x32_bf16(a1, b1, acc[1][1], 0, 0, 0);
        acc[1][2] = __builtin_amdgcn_mfma_f32_16x16x32_bf16(a1, b2, acc[1][2], 0, 0, 0);
        acc[1][3] = __builtin_amdgcn_mfma_f32_16x16x32_bf16(a1, b3, acc[1][3], 0, 0, 0);

        __syncthreads();   // waves done with Bbuf; next slice's DMA drained
    }

    // epilogue: C/D layout col=lane&15, row=(lane>>4)*4+reg (round-1-validated)
    const int colbase = ntile * 128 + n0l + fr;
    #pragma unroll
    for (int mt = 0; mt < 2; ++mt) {
        #pragma unroll
        for (int r = 0; r < 4; ++r) {
            const int hrow = m0 + mt * 16 + q * 4 + r;
            float* po = out + ((size_t)b * SS + (size_t)hrow * 128 + sc) * EE + colbase;
            po[0 * 16] = acc[mt][0][r];
            po[1 * 16] = acc[mt][1][r];
            po[2 * 16] = acc[mt][2][r];
            po[3 * 16] = acc[mt][3][r];
        }
    }
}

// ---------- fallback (round-1 kernel, used only if ws too small) ----------
#define AS 520
#define WSF 40
__global__ __launch_bounds__(256, 2)
void qmha_fused_fb(const float* __restrict__ x, const float* __restrict__ theta,
                   const float* __restrict__ W, float* __restrict__ out)
{
    __shared__ __attribute__((aligned(16))) unsigned short A_lds[HH * AS];
    __shared__ __attribute__((aligned(16))) unsigned short W_lds[128 * WSF];
    const int bx = blockIdx.x;
    const int ntile = (bx >> 3) & 3;
    const int p = ((bx >> 5) << 3) | (bx & 7);
    const int b = p >> 7;
    const int sc = p & 127;
    const int t = threadIdx.x, lane = t & 63, wid = t >> 6;
    const int wn = t >> 1, wk = (t & 1) * 16;
    const float* Wbase = W + (size_t)(ntile * 128 + wn) * EE + wk;
    float4v wv0 = *(const float4v*)(Wbase + 0);
    float4v wv1 = *(const float4v*)(Wbase + 4);
    float4v wv2 = *(const float4v*)(Wbase + 8);
    float4v wv3 = *(const float4v*)(Wbase + 12);
    const float th0 = theta[0], th1 = theta[1], th2 = theta[2], th3 = theta[3];
    const float th4 = theta[4], th5 = theta[5], th6 = theta[6], th7 = theta[7];
    {
        const float* xb = x + ((size_t)b * SS + (size_t)sc * 64) * EE + lane * 8;
        #pragma unroll
        for (int it = 0; it < 16; ++it) {
            const int s_loc = wid * 16 + it;
            const float* px = xb + (size_t)s_loc * EE;
            float4v v0 = *(const float4v*)(px);
            float4v v1 = *(const float4v*)(px + 4);
            float c0 = __cosf(v0.x + th0), c1 = __cosf(v0.y + th1);
            float c2 = __cosf(v0.z + th2), c3 = __cosf(v0.w + th3);
            float c4 = __cosf(v1.x + th4), c5 = __cosf(v1.y + th5);
            float c6 = __cosf(v1.z + th6), c7 = __cosf(v1.w + th7);
            uint4v pk = { pack2(c0,c1), pack2(c2,c3), pack2(c4,c5), pack2(c6,c7) };
            *(uint4v*)&A_lds[lane * AS + s_loc * 8] = pk;
        }
    }
    float4v acc[2][4];
    #pragma unroll
    for (int i = 0; i < 2; ++i)
        #pragma unroll
        for (int j = 0; j < 4; ++j)
            acc[i][j] = (float4v){0.f, 0.f, 0.f, 0.f};
    const int m0 = (wid >> 1) * 32, n0l = (wid & 1) * 64;
    const int fr = lane & 15, q = lane >> 4;
    const unsigned short* Arow0 = &A_lds[(m0 + fr) * AS + q * 8];
    const unsigned short* Arow1 = Arow0 + 16 * AS;
    const unsigned short* Wrow  = &W_lds[(n0l + fr) * WSF + q * 8];
    for (int kb = 0; kb < NKB; ++kb) {
        __syncthreads();
        {
            uint4v lo = { pack2(wv0.x, wv0.y), pack2(wv0.z, wv0.w),
                          pack2(wv1.x, wv1.y), pack2(wv1.z, wv1.w) };
            uint4v hi = { pack2(wv2.x, wv2.y), pack2(wv2.z, wv2.w),
                          pack2(wv3.x, wv3.y), pack2(wv3.z, wv3.w) };
            *(uint4v*)&W_lds[wn * WSF + wk]     = lo;
            *(uint4v*)&W_lds[wn * WSF + wk + 8] = hi;
        }
        if (kb < NKB - 1) {
            const float* Wn = Wbase + (size_t)(kb + 1) * 32;
            wv0 = *(const float4v*)(Wn + 0);
            wv1 = *(const float4v*)(Wn + 4);
            wv2 = *(const float4v*)(Wn + 8);
            wv3 = *(const float4v*)(Wn + 12);
        }
        __syncthreads();
        short8 a0 = *(const short8*)(Arow0 + kb * 32);
        short8 a1 = *(const short8*)(Arow1 + kb * 32);
        short8 b0 = *(const short8*)(Wrow + 0 * 16 * WSF);
        short8 b1 = *(const short8*)(Wrow + 1 * 16 * WSF);
        short8 b2 = *(const short8*)(Wrow + 2 * 16 * WSF);
        short8 b3 = *(const short8*)(Wrow + 3 * 16 * WSF);
        acc[0][0] = __builtin_amdgcn_mfma_f32_16x16x32_bf16(a0, b0, acc[0][0], 0, 0, 0);
        acc[0][1] = __builtin_amdgcn_mfma_f32_16x16x32_bf16(a0, b1, acc[0][1], 0, 0, 0);
        acc[0][2] = __builtin_amdgcn_mfma_f32_16x16x32_bf16(a0, b2, acc[0][2], 0, 0, 0);
        acc[0][3] = __builtin_amdgcn_mfma_f32_16x16x32_bf16(a0, b3, acc[0][3], 0, 0, 0);
        acc[1][0] = __builtin_amdgcn_mfma_f32_16x16x32_bf16(a1, b0, acc[1][0], 0, 0, 0);
        acc[1][1] = __builtin_amdgcn_mfma_f32_16x16x32_bf16(a1, b1, acc[1][1], 0, 0, 0);
        acc[1][2] = __builtin_amdgcn_mfma_f32_16x16x32_bf16(a1, b2, acc[1][2], 0, 0, 0);
        acc[1][3] = __builtin_amdgcn_mfma_f32_16x16x32_bf16(a1, b3, acc[1][3], 0, 0, 0);
    }
    const int colbase = ntile * 128 + n0l + fr;
    #pragma unroll
    for (int mt = 0; mt < 2; ++mt) {
        #pragma unroll
        for (int r = 0; r < 4; ++r) {
            const int hrow = m0 + mt * 16 + q * 4 + r;
            float* po = out + ((size_t)b * SS + (size_t)hrow * 128 + sc) * EE + colbase;
            po[0 * 16] = acc[mt][0][r];
            po[1 * 16] = acc[mt][1][r];
            po[2 * 16] = acc[mt][2][r];
            po[3 * 16] = acc[mt][3][r];
        }
    }
}

extern "C" void kernel_launch(void* const* d_in, const int* in_sizes, int n_in,
                              void* d_out, int out_size, void* d_ws, size_t ws_size,
                              hipStream_t stream) {
    const float* x     = (const float*)d_in[0];
    const float* theta = (const float*)d_in[1];
    const float* W     = (const float*)d_in[2];
    float* out         = (float*)d_out;

    if (ws_size >= (size_t)EE * EE * sizeof(unsigned short)) {
        unsigned short* Wws = (unsigned short*)d_ws;
        w_prep<<<dim3(256), dim3(256), 0, stream>>>(W, Wws);
        qmha_fused2<<<dim3(4096), dim3(256), 0, stream>>>(x, theta, Wws, out);
    } else {
        qmha_fused_fb<<<dim3(4096), dim3(256), 0, stream>>>(x, theta, W, out);
    }
}